// Round 7
// baseline (119.634 us; speedup 1.0000x reference)
//
#include <hip/hip_runtime.h>
#include <math.h>

typedef float f32x4 __attribute__((ext_vector_type(4)));

// ---------------------------------------------------------------------------
// Kernel 0: build the 8x8 complex unitary U of the 2-layer VQC from the 12
// angles (verified R1-R4). Lane j (j<8) evolves basis state e_j; column j of
// U is the result. ws[0..63]=Re(U)[i*8+j], ws[64..127]=Im(U). Wire0 = MSB.
// ---------------------------------------------------------------------------
__global__ __launch_bounds__(64) void vqc_build_u(const float* __restrict__ wq,
                                                  float* __restrict__ Uws) {
  const int j = threadIdx.x;
  if (j >= 8) return;
  float ar[8], ai[8];
#pragma unroll
  for (int i = 0; i < 8; ++i) { ar[i] = (i == j) ? 1.f : 0.f; ai[i] = 0.f; }

#pragma unroll
  for (int l = 0; l < 2; ++l) {
#pragma unroll
    for (int q = 0; q < 3; ++q) {           // RY
      const float th = 0.5f * wq[l * 6 + q];
      const float c = cosf(th), s = sinf(th);
      const int bit = 4 >> q;
#pragma unroll
      for (int i0 = 0; i0 < 8; ++i0) {
        if (i0 & bit) continue;
        const int i1 = i0 | bit;
        const float r0 = ar[i0], m0 = ai[i0], r1 = ar[i1], m1 = ai[i1];
        ar[i0] = c * r0 - s * r1;  ai[i0] = c * m0 - s * m1;
        ar[i1] = s * r0 + c * r1;  ai[i1] = s * m0 + c * m1;
      }
    }
#pragma unroll
    for (int q = 0; q < 3; ++q) {           // RZ
      const float th = 0.5f * wq[l * 6 + 3 + q];
      const float c = cosf(th), s = sinf(th);
      const int bit = 4 >> q;
#pragma unroll
      for (int i = 0; i < 8; ++i) {
        const float r = ar[i], m = ai[i];
        if (i & bit) { ar[i] = r * c - m * s;  ai[i] = m * c + r * s; }
        else         { ar[i] = r * c + m * s;  ai[i] = m * c - r * s; }
      }
    }
#pragma unroll
    for (int k = 0; k < 3; ++k) {           // CNOTs (4,2),(2,1),(1,4)
      const int cb = (k == 0) ? 4 : (k == 1) ? 2 : 1;
      const int tb = (k == 0) ? 2 : (k == 1) ? 1 : 4;
#pragma unroll
      for (int i = 0; i < 8; ++i) {
        if ((i & cb) && !(i & tb)) {
          const int i1 = i | tb;
          float t;
          t = ar[i]; ar[i] = ar[i1]; ar[i1] = t;
          t = ai[i]; ai[i] = ai[i1]; ai[i1] = t;
        }
      }
    }
  }
#pragma unroll
  for (int i = 0; i < 8; ++i) {
    Uws[i * 8 + j]      = ar[i];
    Uws[64 + i * 8 + j] = ai[i];
  }
}

// ---------------------------------------------------------------------------
// Fused kernel (R3 structure, 114.86us proven) + ONE change: cross-batch
// software pipeline. Slot t's registers are consumed by row t's FMA block and
// immediately re-loaded with row t of the NEXT batch, so ~16 loads/wave stay
// in flight continuously (incl. during the reduce chains and the epilogue),
// instead of a 16KB burst followed by a ~2000-cycle memory-silent phase.
// Each prefetched load has a full batch-compute (> HBM latency) to return.
// On the last iteration the prefetch is redirected to batch 0 (L3-resident,
// ~zero extra HBM traffic); the data is never consumed.
// ---------------------------------------------------------------------------
template<bool GUARD>
__global__ __launch_bounds__(256, 2) void vqc_fused(const float* __restrict__ x,
                                                    const float* __restrict__ W,
                                                    const float* __restrict__ bias,
                                                    const float* __restrict__ Uws,
                                                    float* __restrict__ out, int B) {
  const int lane = threadIdx.x & 63;
  const int wid  = blockIdx.x * (blockDim.x >> 6) + (threadIdx.x >> 6);
  const int nw   = gridDim.x * (blockDim.x >> 6);
  const bool b0 = (lane & 1) != 0;
  const bool b1 = (lane & 2) != 0;
  const bool b2 = (lane & 4) != 0;
  const int grp = lane >> 3;
  const int myv = ((lane & 1) << 2) | (lane & 2) | ((lane >> 2) & 1);  // bitrev3(lane&7)

  // W (8x512) resident in 64 VGPRs/lane
  float w0[8][4], w1[8][4];
#pragma unroll
  for (int v = 0; v < 8; ++v) {
    const f32x4 a = *(const f32x4*)(W + v * 512 + lane * 4);
    const f32x4 b = *(const f32x4*)(W + v * 512 + 256 + lane * 4);
    w0[v][0] = a.x; w0[v][1] = a.y; w0[v][2] = a.z; w0[v][3] = a.w;
    w1[v][0] = b.x; w1[v][1] = b.y; w1[v][2] = b.z; w1[v][3] = b.w;
  }
  float Ur[8], Ui[8];
#pragma unroll
  for (int i = 0; i < 8; ++i) {
    Ur[i] = Uws[i * 8 + myv];
    Ui[i] = Uws[64 + i * 8 + myv];
  }
  const float bv = bias[myv];

  const int nbatch = (B + 7) >> 3;
  int rb = wid;
  if (rb < nbatch) {
    f32x4 xa[8], xb[8];
    // ---- prologue: load slots for the first batch ----
    {
      const size_t r0 = (size_t)rb << 3;
#pragma unroll
      for (int t = 0; t < 8; ++t) {
        size_t r = r0 + t;
        if (GUARD) r = (r < (size_t)B) ? r : (size_t)(B - 1);
        const f32x4* xr = (const f32x4*)(x + r * 512);
        xa[t] = xr[lane];
        xb[t] = xr[64 + lane];
      }
    }

    for (; rb < nbatch; rb += nw) {
      const size_t r0 = (size_t)rb << 3;
      // next batch to prefetch; batch 0 (L3-hot, unused) when none remains
      const int nrb = (rb + nw < nbatch) ? (rb + nw) : 0;
      const size_t nr0 = (size_t)nrb << 3;

      float myd = 0.f;  // this lane's dot: row r0+grp, vector myv
#pragma unroll
      for (int t = 0; t < 8; ++t) {
        float acc[8];
#pragma unroll
        for (int v = 0; v < 8; ++v) {
          float s = xa[t].x * w0[v][0];
          s = fmaf(xa[t].y, w0[v][1], s);
          s = fmaf(xa[t].z, w0[v][2], s);
          s = fmaf(xa[t].w, w0[v][3], s);
          s = fmaf(xb[t].x, w1[v][0], s);
          s = fmaf(xb[t].y, w1[v][1], s);
          s = fmaf(xb[t].z, w1[v][2], s);
          s = fmaf(xb[t].w, w1[v][3], s);
          acc[v] = s;
        }
        // ---- slot t consumed: re-issue its loads for the next batch ----
        {
          size_t rn = nr0 + t;
          if (GUARD) rn = (rn < (size_t)B) ? rn : (size_t)(B - 1);
          const f32x4* xrn = (const f32x4*)(x + rn * 512);
          xa[t] = xrn[lane];
          xb[t] = xrn[64 + lane];
        }
        // halving reduce: 8 vals over 64 lanes -> 1 val/lane (v = myv)
        float s4[4];
#pragma unroll
        for (int i = 0; i < 4; ++i) {
          const float keep = b0 ? acc[i + 4] : acc[i];
          const float send = b0 ? acc[i] : acc[i + 4];
          s4[i] = keep + __shfl_xor(send, 1, 64);
        }
        float s2[2];
#pragma unroll
        for (int i = 0; i < 2; ++i) {
          const float keep = b1 ? s4[i + 2] : s4[i];
          const float send = b1 ? s4[i] : s4[i + 2];
          s2[i] = keep + __shfl_xor(send, 2, 64);
        }
        const float keep = b2 ? s2[1] : s2[0];
        const float send = b2 ? s2[0] : s2[1];
        float s1 = keep + __shfl_xor(send, 4, 64);
        s1 += __shfl_xor(s1, 8, 64);
        s1 += __shfl_xor(s1, 16, 64);
        s1 += __shfl_xor(s1, 32, 64);
        myd = (grp == t) ? s1 : myd;
      }

      // ---- epilogue: 8 rows in parallel (group = row, lane-in-group = myv) ----
      const size_t row = r0 + grp;
      const float p = tanhf(myd + bv);
      float ss = p * p;
      ss += __shfl_xor(ss, 1, 64);
      ss += __shfl_xor(ss, 2, 64);
      ss += __shfl_xor(ss, 4, 64);
      const float av = p * (1.0f / fmaxf(sqrtf(ss), 1e-12f));

      float q[16];
#pragma unroll
      for (int i = 0; i < 8; ++i) {
        q[2 * i]     = Ur[i] * av;
        q[2 * i + 1] = Ui[i] * av;
      }
      float n8[8];
#pragma unroll
      for (int i = 0; i < 8; ++i) {
        const float k1 = b0 ? q[i + 8] : q[i];
        const float s1v = b0 ? q[i] : q[i + 8];
        n8[i] = k1 + __shfl_xor(s1v, 1, 64);
      }
      float n4[4];
#pragma unroll
      for (int i = 0; i < 4; ++i) {
        const float k2 = b1 ? n8[i + 4] : n8[i];
        const float s2v = b1 ? n8[i] : n8[i + 4];
        n4[i] = k2 + __shfl_xor(s2v, 2, 64);
      }
      float n2[2];
#pragma unroll
      for (int i = 0; i < 2; ++i) {
        const float k3 = b2 ? n4[i + 2] : n4[i];
        const float s3v = b2 ? n4[i] : n4[i + 2];
        n2[i] = k3 + __shfl_xor(s3v, 4, 64);
      }
      const float pr = n2[0] * n2[0] + n2[1] * n2[1];
      float t0 = (myv & 4) ? -pr : pr;
      float t1 = (myv & 2) ? -pr : pr;
      float t2 = (myv & 1) ? -pr : pr;
#pragma unroll
      for (int m = 1; m <= 4; m <<= 1) {
        t0 += __shfl_xor(t0, m, 64);
        t1 += __shfl_xor(t1, m, 64);
        t2 += __shfl_xor(t2, m, 64);
      }
      if (!GUARD || row < (size_t)B) {
        float* o = out + row * 11;
        o[myv] = p;
        if (myv < 3) o[8 + myv] = (myv == 0) ? t0 : ((myv == 1) ? t1 : t2);
      }
    }
  }
}

extern "C" void kernel_launch(void* const* d_in, const int* in_sizes, int n_in,
                              void* d_out, int out_size, void* d_ws, size_t ws_size,
                              hipStream_t stream) {
  const float* x  = (const float*)d_in[0];   // (B, 512)
  const float* W  = (const float*)d_in[1];   // (8, 512)
  const float* b  = (const float*)d_in[2];   // (8,)
  const float* wq = (const float*)d_in[3];   // (2, 2, 3)
  float* out = (float*)d_out;                // (B, 11)
  float* Uws = (float*)d_ws;                 // 128 floats

  const int B = in_sizes[0] / 512;

  vqc_build_u<<<1, 64, 0, stream>>>(wq, Uws);
  if (B & 7)
    vqc_fused<true><<<2048, 256, 0, stream>>>(x, W, b, Uws, out, B);
  else
    vqc_fused<false><<<2048, 256, 0, stream>>>(x, W, b, Uws, out, B);
}

// Round 8
// 112.362 us; speedup vs baseline: 1.0647x; 1.0647x over previous
//
#include <hip/hip_runtime.h>
#include <math.h>

typedef float f32x4 __attribute__((ext_vector_type(4)));

// ---------------------------------------------------------------------------
// Fully-fused single kernel. Structure = R3 (proven 114.86us): W in 64
// VGPRs/lane, 8-row batch preload (16KB/wave burst), halving-butterfly
// reduce (myv = bitrev3(lane&7), grp = lane>>3), lane-parallel epilogue.
// ONE change vs R3: the 8x8 complex unitary U of the 2-layer VQC (a fixed
// function of the 12 angles) is built inline -- each lane evolves basis
// state |myv> through RY/RZ/CNOT layers, producing exactly column myv of U,
// which is all the epilogue needs. Removes the serial build_u dispatch and
// its inter-kernel gap from the graph (~3-6us). Cost: ~150 VALU + 12 trig
// per thread, once, amortized over ~32 batches/wave.
// ---------------------------------------------------------------------------
template<bool GUARD>
__global__ __launch_bounds__(256, 2) void vqc_fused(const float* __restrict__ x,
                                                    const float* __restrict__ W,
                                                    const float* __restrict__ bias,
                                                    const float* __restrict__ wq,
                                                    float* __restrict__ out, int B) {
  const int lane = threadIdx.x & 63;
  const int wid  = blockIdx.x * (blockDim.x >> 6) + (threadIdx.x >> 6);
  const int nw   = gridDim.x * (blockDim.x >> 6);
  const bool b0 = (lane & 1) != 0;
  const bool b1 = (lane & 2) != 0;
  const bool b2 = (lane & 4) != 0;
  const int grp = lane >> 3;
  const int myv = ((lane & 1) << 2) | (lane & 2) | ((lane >> 2) & 1);  // bitrev3(lane&7)

  // W (8x512) resident in 64 VGPRs/lane; lane covers cols lane*4..+3, 256+lane*4..+3
  float w0[8][4], w1[8][4];
#pragma unroll
  for (int v = 0; v < 8; ++v) {
    const f32x4 a = *(const f32x4*)(W + v * 512 + lane * 4);
    const f32x4 b = *(const f32x4*)(W + v * 512 + 256 + lane * 4);
    w0[v][0] = a.x; w0[v][1] = a.y; w0[v][2] = a.z; w0[v][3] = a.w;
    w1[v][0] = b.x; w1[v][1] = b.y; w1[v][2] = b.z; w1[v][3] = b.w;
  }
  const float bv = bias[myv];

  // ---- inline U-build (correctness-verified in R6): evolve |myv> through
  // the circuit -> column myv of U. Wire 0 = MSB: qubit q <-> bit (4>>q).
  // Per layer: RY(q=0,1,2), RZ(q=0,1,2), CNOT (4,2),(2,1),(1,4).
  float Ur[8], Ui[8];
#pragma unroll
  for (int i = 0; i < 8; ++i) { Ur[i] = (i == myv) ? 1.f : 0.f; Ui[i] = 0.f; }
#pragma unroll
  for (int l = 0; l < 2; ++l) {
#pragma unroll
    for (int q = 0; q < 3; ++q) {           // RY
      const float th = 0.5f * wq[l * 6 + q];
      const float c = cosf(th), s = sinf(th);
      const int bit = 4 >> q;
#pragma unroll
      for (int i0 = 0; i0 < 8; ++i0) {
        if (i0 & bit) continue;
        const int i1 = i0 | bit;
        const float r0 = Ur[i0], m0 = Ui[i0], r1 = Ur[i1], m1 = Ui[i1];
        Ur[i0] = c * r0 - s * r1;  Ui[i0] = c * m0 - s * m1;
        Ur[i1] = s * r0 + c * r1;  Ui[i1] = s * m0 + c * m1;
      }
    }
#pragma unroll
    for (int q = 0; q < 3; ++q) {           // RZ
      const float th = 0.5f * wq[l * 6 + 3 + q];
      const float c = cosf(th), s = sinf(th);
      const int bit = 4 >> q;
#pragma unroll
      for (int i = 0; i < 8; ++i) {
        const float r = Ur[i], m = Ui[i];
        if (i & bit) { Ur[i] = r * c - m * s;  Ui[i] = m * c + r * s; }
        else         { Ur[i] = r * c + m * s;  Ui[i] = m * c - r * s; }
      }
    }
#pragma unroll
    for (int k = 0; k < 3; ++k) {           // CNOTs
      const int cb = (k == 0) ? 4 : (k == 1) ? 2 : 1;
      const int tb = (k == 0) ? 2 : (k == 1) ? 1 : 4;
#pragma unroll
      for (int i = 0; i < 8; ++i) {
        if ((i & cb) && !(i & tb)) {
          const int i1 = i | tb;
          float t;
          t = Ur[i]; Ur[i] = Ur[i1]; Ur[i1] = t;
          t = Ui[i]; Ui[i] = Ui[i1]; Ui[i1] = t;
        }
      }
    }
  }

  const int nbatch = (B + 7) >> 3;
  for (int rb = wid; rb < nbatch; rb += nw) {
    const size_t r0 = (size_t)rb << 3;

    // ---- preload the whole 8-row batch: 16 KB/wave in flight ----
    f32x4 xa[8], xb[8];
#pragma unroll
    for (int t = 0; t < 8; ++t) {
      size_t r = r0 + t;
      if (GUARD) r = (r < (size_t)B) ? r : (size_t)(B - 1);
      const f32x4* xr = (const f32x4*)(x + r * 512);
      xa[t] = xr[lane];
      xb[t] = xr[64 + lane];
    }

    float myd = 0.f;  // this lane's dot: row r0+grp, vector myv
#pragma unroll
    for (int t = 0; t < 8; ++t) {
      float acc[8];
#pragma unroll
      for (int v = 0; v < 8; ++v) {
        float s = xa[t].x * w0[v][0];
        s = fmaf(xa[t].y, w0[v][1], s);
        s = fmaf(xa[t].z, w0[v][2], s);
        s = fmaf(xa[t].w, w0[v][3], s);
        s = fmaf(xb[t].x, w1[v][0], s);
        s = fmaf(xb[t].y, w1[v][1], s);
        s = fmaf(xb[t].z, w1[v][2], s);
        s = fmaf(xb[t].w, w1[v][3], s);
        acc[v] = s;
      }
      // halving reduce: 8 vals over 64 lanes -> 1 val/lane (v = myv)
      float s4[4];
#pragma unroll
      for (int i = 0; i < 4; ++i) {
        const float keep = b0 ? acc[i + 4] : acc[i];
        const float send = b0 ? acc[i] : acc[i + 4];
        s4[i] = keep + __shfl_xor(send, 1, 64);
      }
      float s2[2];
#pragma unroll
      for (int i = 0; i < 2; ++i) {
        const float keep = b1 ? s4[i + 2] : s4[i];
        const float send = b1 ? s4[i] : s4[i + 2];
        s2[i] = keep + __shfl_xor(send, 2, 64);
      }
      const float keep = b2 ? s2[1] : s2[0];
      const float send = b2 ? s2[0] : s2[1];
      float s1 = keep + __shfl_xor(send, 4, 64);
      s1 += __shfl_xor(s1, 8, 64);
      s1 += __shfl_xor(s1, 16, 64);
      s1 += __shfl_xor(s1, 32, 64);
      myd = (grp == t) ? s1 : myd;
    }

    // ---- epilogue: 8 rows in parallel (group = row, lane-in-group = myv) ----
    const size_t row = r0 + grp;
    const float p = tanhf(myd + bv);
    float ss = p * p;
    ss += __shfl_xor(ss, 1, 64);
    ss += __shfl_xor(ss, 2, 64);
    ss += __shfl_xor(ss, 4, 64);
    const float av = p * (1.0f / fmaxf(sqrtf(ss), 1e-12f));

    // complex matvec: lane contributes column myv; halving-reduce the
    // 16-vector [cr0,ci0,cr1,ci1,...] over the 8-lane group
    float q[16];
#pragma unroll
    for (int i = 0; i < 8; ++i) {
      q[2 * i]     = Ur[i] * av;
      q[2 * i + 1] = Ui[i] * av;
    }
    float n8[8];
#pragma unroll
    for (int i = 0; i < 8; ++i) {
      const float k1 = b0 ? q[i + 8] : q[i];
      const float s1v = b0 ? q[i] : q[i + 8];
      n8[i] = k1 + __shfl_xor(s1v, 1, 64);
    }
    float n4[4];
#pragma unroll
    for (int i = 0; i < 4; ++i) {
      const float k2 = b1 ? n8[i + 4] : n8[i];
      const float s2v = b1 ? n8[i] : n8[i + 4];
      n4[i] = k2 + __shfl_xor(s2v, 2, 64);
    }
    float n2[2];
#pragma unroll
    for (int i = 0; i < 2; ++i) {
      const float k3 = b2 ? n4[i + 2] : n4[i];
      const float s3v = b2 ? n4[i] : n4[i + 2];
      n2[i] = k3 + __shfl_xor(s3v, 4, 64);
    }
    // lane holds cr,ci for state index i = myv
    const float pr = n2[0] * n2[0] + n2[1] * n2[1];
    // <Z_q>: sign by bit (4>>q) of state index
    float t0 = (myv & 4) ? -pr : pr;
    float t1 = (myv & 2) ? -pr : pr;
    float t2 = (myv & 1) ? -pr : pr;
#pragma unroll
    for (int m = 1; m <= 4; m <<= 1) {
      t0 += __shfl_xor(t0, m, 64);
      t1 += __shfl_xor(t1, m, 64);
      t2 += __shfl_xor(t2, m, 64);
    }
    if (!GUARD || row < (size_t)B) {
      float* o = out + row * 11;
      o[myv] = p;
      if (myv < 3) o[8 + myv] = (myv == 0) ? t0 : ((myv == 1) ? t1 : t2);
    }
  }
}

extern "C" void kernel_launch(void* const* d_in, const int* in_sizes, int n_in,
                              void* d_out, int out_size, void* d_ws, size_t ws_size,
                              hipStream_t stream) {
  const float* x  = (const float*)d_in[0];   // (B, 512)
  const float* W  = (const float*)d_in[1];   // (8, 512)
  const float* b  = (const float*)d_in[2];   // (8,)
  const float* wq = (const float*)d_in[3];   // (2, 2, 3)
  float* out = (float*)d_out;                // (B, 11)

  const int B = in_sizes[0] / 512;

  if (B & 7)
    vqc_fused<true><<<2048, 256, 0, stream>>>(x, W, b, wq, out, B);
  else
    vqc_fused<false><<<2048, 256, 0, stream>>>(x, W, b, wq, out, B);
}